// Round 2
// baseline (2583.325 us; speedup 1.0000x reference)
//
#include <hip/hip_runtime.h>
#include <hip/hip_bf16.h>

#define BATCH 128
#define SEQT  200
#define BT    25600      // BATCH*SEQT
#define HDIM  128
#define NI    16         // items per block in item_emb

__device__ __forceinline__ float wave_reduce_sum(float v) {
  #pragma unroll
  for (int o = 32; o; o >>= 1) v += __shfl_xor(v, o);
  return v;
}
__device__ __forceinline__ float wave_reduce_max(float v) {
  #pragma unroll
  for (int o = 32; o; o >>= 1) v = fmaxf(v, __shfl_xor(v, o));
  return v;
}

// ---------------- item embedding tower ----------------
// per block: NI items. LDS rows (stride 772 -> (772*r+k)&31=(4r+k)&31, conflict-free
// 4-distinct-row broadcast within a wave), LN in place, then K x 64 GEMM.
template<int K>
__device__ void emb_phase(const float* __restrict__ table,
                          const float* __restrict__ lns, const float* __restrict__ lnb,
                          const float* __restrict__ w, const float* __restrict__ bvec,
                          const int* ids, float (*buf)[772], float (*cat)[132],
                          float (*stats)[2], int cofs)
{
  const int tid = threadIdx.x;
  constexpr int RF4 = K / 4;
  constexpr int NF4 = NI * RF4;
  for (int e = tid; e < NF4; e += 256) {
    int r = e / RF4, k4 = e - r * RF4;
    *(float4*)&buf[r][k4 * 4] = *(const float4*)(table + (size_t)ids[r] * K + k4 * 4);
  }
  __syncthreads();
  const int wv = tid >> 6, lane = tid & 63;
  for (int r = wv * 4; r < wv * 4 + 4; ++r) {
    float s = 0.f, sq = 0.f;
    for (int k = lane; k < K; k += 64) { float xv = buf[r][k]; s += xv; sq += xv * xv; }
    s = wave_reduce_sum(s); sq = wave_reduce_sum(sq);
    if (lane == 0) {
      float mu = s * (1.f / K);
      stats[r][0] = mu;
      stats[r][1] = rsqrtf(sq * (1.f / K) - mu * mu + 1e-5f);
    }
  }
  __syncthreads();
  for (int e = tid; e < NF4; e += 256) {
    int r = e / RF4, k4 = e - r * RF4;
    float mu = stats[r][0], rs = stats[r][1];
    float4 x = *(float4*)&buf[r][k4 * 4];
    float4 g = *(const float4*)(lns + k4 * 4);
    float4 bb = *(const float4*)(lnb + k4 * 4);
    x.x = (x.x - mu) * rs * g.x + bb.x;
    x.y = (x.y - mu) * rs * g.y + bb.y;
    x.z = (x.z - mu) * rs * g.z + bb.z;
    x.w = (x.w - mu) * rs * g.w + bb.w;
    *(float4*)&buf[r][k4 * 4] = x;
  }
  __syncthreads();
  // GEMM: row r = tid>>4 (16 rows), cols jg*4..+3 (jg = tid&15)
  const int r = tid >> 4, jg = tid & 15;
  float4 acc = make_float4(0.f, 0.f, 0.f, 0.f);
  const float* wp = w + jg * 4;
  #pragma unroll 4
  for (int k = 0; k < K; ++k) {
    float xv = buf[r][k];
    float4 wv4 = *(const float4*)(wp + (size_t)k * 64);
    acc.x = fmaf(xv, wv4.x, acc.x);
    acc.y = fmaf(xv, wv4.y, acc.y);
    acc.z = fmaf(xv, wv4.z, acc.z);
    acc.w = fmaf(xv, wv4.w, acc.w);
  }
  float4 bb = *(const float4*)(bvec + jg * 4);
  acc.x = fmaxf(acc.x + bb.x, 0.f);
  acc.y = fmaxf(acc.y + bb.y, 0.f);
  acc.z = fmaxf(acc.z + bb.z, 0.f);
  acc.w = fmaxf(acc.w + bb.w, 0.f);
  *(float4*)&cat[r][cofs + jg * 4] = acc;
  __syncthreads();
}

__global__ __launch_bounds__(256) void item_emb_kernel(
    const int* __restrict__ log_seqs, const int* __restrict__ pos_seqs, const int* __restrict__ neg_seqs,
    const float* __restrict__ txt_table, const float* __restrict__ img_table,
    const float* __restrict__ txt_ln_s, const float* __restrict__ txt_ln_b,
    const float* __restrict__ txt_w, const float* __restrict__ txt_b,
    const float* __restrict__ img_ln_s, const float* __restrict__ img_ln_b,
    const float* __restrict__ img_w, const float* __restrict__ img_b,
    const float* __restrict__ fuse_w, const float* __restrict__ fuse_b,
    float* __restrict__ emb_out)
{
  __shared__ float buf[NI][772];
  __shared__ float cat[NI][132];
  __shared__ float stats[NI][2];
  __shared__ int ids[NI];
  const int tid = threadIdx.x;
  const int item0 = blockIdx.x * NI;
  if (tid < NI) {
    int idx = item0 + tid;
    int seq = idx / BT, pos = idx - seq * BT;
    const int* sp = (seq == 0) ? log_seqs : (seq == 1 ? pos_seqs : neg_seqs);
    ids[tid] = sp[pos];
  }
  __syncthreads();
  emb_phase<768>(txt_table, txt_ln_s, txt_ln_b, txt_w, txt_b, ids, buf, cat, stats, 0);
  emb_phase<512>(img_table, img_ln_s, img_ln_b, img_w, img_b, ids, buf, cat, stats, 64);
  // fuse GEMM 128x128, relu
  const int r = tid >> 4, jg = tid & 15;
  float a0x=0.f,a0y=0.f,a0z=0.f,a0w=0.f, a1x=0.f,a1y=0.f,a1z=0.f,a1w=0.f;
  #pragma unroll 4
  for (int k = 0; k < 128; ++k) {
    float xv = cat[r][k];
    float4 w0 = *(const float4*)(fuse_w + (size_t)k * 128 + jg * 4);
    float4 w1 = *(const float4*)(fuse_w + (size_t)k * 128 + 64 + jg * 4);
    a0x = fmaf(xv, w0.x, a0x); a0y = fmaf(xv, w0.y, a0y);
    a0z = fmaf(xv, w0.z, a0z); a0w = fmaf(xv, w0.w, a0w);
    a1x = fmaf(xv, w1.x, a1x); a1y = fmaf(xv, w1.y, a1y);
    a1z = fmaf(xv, w1.z, a1z); a1w = fmaf(xv, w1.w, a1w);
  }
  float4 b0 = *(const float4*)(fuse_b + jg * 4);
  float4 b1 = *(const float4*)(fuse_b + 64 + jg * 4);
  float4 o0, o1;
  o0.x = fmaxf(a0x + b0.x, 0.f); o0.y = fmaxf(a0y + b0.y, 0.f);
  o0.z = fmaxf(a0z + b0.z, 0.f); o0.w = fmaxf(a0w + b0.w, 0.f);
  o1.x = fmaxf(a1x + b1.x, 0.f); o1.y = fmaxf(a1y + b1.y, 0.f);
  o1.z = fmaxf(a1z + b1.z, 0.f); o1.w = fmaxf(a1w + b1.w, 0.f);
  float* op = emb_out + (size_t)(item0 + r) * HDIM;
  *(float4*)(op + jg * 4) = o0;
  *(float4*)(op + 64 + jg * 4) = o1;
}

// ---------------- x0 = emb_log*sqrt(H) + pos_e, masked ----------------
__global__ __launch_bounds__(256) void x0_kernel(const float* __restrict__ emb_log,
    const float* __restrict__ pos_e, const int* __restrict__ log_seqs, float* __restrict__ x)
{
  int e = blockIdx.x * 256 + threadIdx.x;  // float4 index; total BT*32
  int row = e >> 5, c4 = e & 31;
  int t = row % SEQT;
  float4 v = *(const float4*)(emb_log + (size_t)row * HDIM + c4 * 4);
  float4 p = *(const float4*)(pos_e + (size_t)t * HDIM + c4 * 4);
  float kp = (log_seqs[row] != 0) ? 1.f : 0.f;
  const float s = 11.313708498984761f;  // sqrt(128)
  float4 o;
  o.x = (v.x * s + p.x) * kp;
  o.y = (v.y * s + p.y) * kp;
  o.z = (v.z * s + p.z) * kp;
  o.w = (v.w * s + p.w) * kp;
  *(float4*)(x + (size_t)row * HDIM + c4 * 4) = o;
}

// ---------------- LayerNorm over 128 (wave per row) ----------------
__global__ __launch_bounds__(256) void ln128_kernel(const float* __restrict__ in,
    const float* __restrict__ g, const float* __restrict__ b, float* __restrict__ out, float eps)
{
  int row = blockIdx.x * 4 + (threadIdx.x >> 6);
  int lane = threadIdx.x & 63;
  const float* p = in + (size_t)row * HDIM;
  float2 v = *(const float2*)(p + lane * 2);
  float s = wave_reduce_sum(v.x + v.y);
  float sq = wave_reduce_sum(v.x * v.x + v.y * v.y);
  float mu = s * (1.f / 128.f);
  float rs = rsqrtf(sq * (1.f / 128.f) - mu * mu + eps);
  float2 gg = *(const float2*)(g + lane * 2), bb = *(const float2*)(b + lane * 2);
  float2 o;
  o.x = (v.x - mu) * rs * gg.x + bb.x;
  o.y = (v.y - mu) * rs * gg.y + bb.y;
  *(float2*)(out + (size_t)row * HDIM + lane * 2) = o;
}

// ---------------- generic [BT,128]x[128,128] GEMM ----------------
__global__ __launch_bounds__(256) void gemm128_kernel(const float* __restrict__ A,
    const float* __restrict__ W, const float* __restrict__ bias,
    const float* __restrict__ addp, const int* __restrict__ mask,
    float* __restrict__ out, int relu)
{
  __shared__ float a_lds[32][132];
  const int tid = threadIdx.x;
  const int row0 = blockIdx.x * 32;
  #pragma unroll
  for (int i = 0; i < 4; ++i) {
    int e = tid + i * 256;
    int r = e >> 5, k4 = e & 31;
    *(float4*)&a_lds[r][k4 * 4] = *(const float4*)(A + (size_t)(row0 + r) * HDIM + k4 * 4);
  }
  __syncthreads();
  const int cg = tid & 15, rg = tid >> 4;
  float acc[2][8];
  #pragma unroll
  for (int i = 0; i < 2; ++i)
    #pragma unroll
    for (int j = 0; j < 8; ++j) acc[i][j] = 0.f;
  const float* wp = W + cg * 8;
  #pragma unroll 2
  for (int k = 0; k < 128; ++k) {
    float av0 = a_lds[rg * 2][k];
    float av1 = a_lds[rg * 2 + 1][k];
    float4 w0 = *(const float4*)(wp + (size_t)k * 128);
    float4 w1 = *(const float4*)(wp + (size_t)k * 128 + 4);
    float wv8[8] = {w0.x, w0.y, w0.z, w0.w, w1.x, w1.y, w1.z, w1.w};
    #pragma unroll
    for (int j = 0; j < 8; ++j) {
      acc[0][j] = fmaf(av0, wv8[j], acc[0][j]);
      acc[1][j] = fmaf(av1, wv8[j], acc[1][j]);
    }
  }
  float4 bb0 = *(const float4*)(bias + cg * 8);
  float4 bb1 = *(const float4*)(bias + cg * 8 + 4);
  float bv[8] = {bb0.x, bb0.y, bb0.z, bb0.w, bb1.x, bb1.y, bb1.z, bb1.w};
  #pragma unroll
  for (int rr = 0; rr < 2; ++rr) {
    int row = row0 + rg * 2 + rr;
    float v[8];
    #pragma unroll
    for (int j = 0; j < 8; ++j) v[j] = acc[rr][j] + bv[j];
    if (relu) {
      #pragma unroll
      for (int j = 0; j < 8; ++j) v[j] = fmaxf(v[j], 0.f);
    }
    if (addp) {
      float4 r0 = *(const float4*)(addp + (size_t)row * HDIM + cg * 8);
      float4 r1 = *(const float4*)(addp + (size_t)row * HDIM + cg * 8 + 4);
      v[0] += r0.x; v[1] += r0.y; v[2] += r0.z; v[3] += r0.w;
      v[4] += r1.x; v[5] += r1.y; v[6] += r1.z; v[7] += r1.w;
    }
    if (mask && mask[row] == 0) {
      #pragma unroll
      for (int j = 0; j < 8; ++j) v[j] = 0.f;
    }
    float4 s0 = {v[0], v[1], v[2], v[3]};
    float4 s1 = {v[4], v[5], v[6], v[7]};
    *(float4*)(out + (size_t)row * HDIM + cg * 8) = s0;
    *(float4*)(out + (size_t)row * HDIM + cg * 8 + 4) = s1;
  }
}

// ---------------- causal attention, one (b,h) per block ----------------
// K/V staged in LDS, XOR-swizzled (d ^ (s&31)) so score reads (lane=s) are
// conflict-free. Wave w handles query rows t = w, w+4, ...
__global__ __launch_bounds__(256) void attn_kernel(const float* __restrict__ q,
    const float* __restrict__ kbuf, const float* __restrict__ vbuf, float* __restrict__ o)
{
  extern __shared__ float smem[];
  float* k_lds = smem;              // 200*64
  float* v_lds = smem + 12800;      // 200*64
  float* q_lds = smem + 25600;      // 4*64
  float* p_lds = smem + 25856;      // 4*64
  const int tid = threadIdx.x;
  const int b = blockIdx.x >> 1, h = blockIdx.x & 1;
  const size_t base = (size_t)b * SEQT * HDIM + h * 64;
  for (int e = tid; e < SEQT * 64; e += 256) {
    int s = e >> 6, d = e & 63;
    int sw = d ^ (s & 31);
    k_lds[s * 64 + sw] = kbuf[base + (size_t)s * HDIM + d];
    v_lds[s * 64 + sw] = vbuf[base + (size_t)s * HDIM + d];
  }
  __syncthreads();
  const int w = tid >> 6, lane = tid & 63;
  for (int t = w; t < SEQT; t += 4) {
    q_lds[w * 64 + lane] = q[base + (size_t)t * HDIM + lane];
    const int nch = (t >> 6) + 1;
    float sc[4], m = -1e30f;
    for (int c = 0; c < nch; ++c) {
      int s = c * 64 + lane;
      if (s <= t) {
        const float* kr = k_lds + s * 64;
        const int sw5 = s & 31;
        float a = 0.f;
        #pragma unroll
        for (int d = 0; d < 64; ++d)
          a = fmaf(q_lds[w * 64 + d], kr[d ^ sw5], a);
        sc[c] = a * 0.125f;   // 1/sqrt(64)
      } else sc[c] = -1e30f;
      m = fmaxf(m, sc[c]);
    }
    m = wave_reduce_max(m);
    float p[4], ssum = 0.f;
    for (int c = 0; c < nch; ++c) {
      int s = c * 64 + lane;
      p[c] = (s <= t) ? __expf(sc[c] - m) : 0.f;
      ssum += p[c];
    }
    ssum = wave_reduce_sum(ssum);
    float inv = 1.f / ssum;
    float oacc = 0.f;
    for (int c = 0; c < nch; ++c) {
      p_lds[w * 64 + lane] = p[c];
      const int smax = min(64, t - c * 64 + 1);
      for (int sp = 0; sp < smax; ++sp) {
        int s = c * 64 + sp;
        oacc = fmaf(p_lds[w * 64 + sp], v_lds[s * 64 + (lane ^ (s & 31))], oacc);
      }
    }
    o[base + (size_t)t * HDIM + lane] = oacc * inv;
  }
}

// ---------------- logits ----------------
__global__ __launch_bounds__(256) void logits_kernel(const float* __restrict__ feats,
    const float* __restrict__ ep, const float* __restrict__ en, float* __restrict__ out)
{
  int row = blockIdx.x * 4 + (threadIdx.x >> 6);
  int lane = threadIdx.x & 63;
  size_t off = (size_t)row * HDIM + lane * 2;
  float2 f = *(const float2*)(feats + off);
  float2 p = *(const float2*)(ep + off);
  float2 n = *(const float2*)(en + off);
  float sp = wave_reduce_sum(f.x * p.x + f.y * p.y);
  float sn = wave_reduce_sum(f.x * n.x + f.y * n.y);
  if (lane == 0) { out[row] = sp; out[BT + row] = sn; }
}

extern "C" void kernel_launch(void* const* d_in, const int* in_sizes, int n_in,
                              void* d_out, int out_size, void* d_ws, size_t ws_size,
                              hipStream_t stream) {
  const int* log_seqs   = (const int*)d_in[0];
  const int* pos_seqs   = (const int*)d_in[1];
  const int* neg_seqs   = (const int*)d_in[2];
  const float* txt_table = (const float*)d_in[3];
  const float* img_table = (const float*)d_in[4];
  const float* txt_ln_s = (const float*)d_in[5];
  const float* txt_ln_b = (const float*)d_in[6];
  const float* txt_w    = (const float*)d_in[7];
  const float* txt_b    = (const float*)d_in[8];
  const float* img_ln_s = (const float*)d_in[9];
  const float* img_ln_b = (const float*)d_in[10];
  const float* img_w    = (const float*)d_in[11];
  const float* img_b    = (const float*)d_in[12];
  const float* fuse_w   = (const float*)d_in[13];
  const float* fuse_b   = (const float*)d_in[14];
  const float* pos_e    = (const float*)d_in[15];
  const float* attn_ln_s = (const float*)d_in[16];
  const float* attn_ln_b = (const float*)d_in[17];
  const float* w_q = (const float*)d_in[18];
  const float* b_q = (const float*)d_in[19];
  const float* w_k = (const float*)d_in[20];
  const float* b_k = (const float*)d_in[21];
  const float* w_v = (const float*)d_in[22];
  const float* b_v = (const float*)d_in[23];
  const float* w_o = (const float*)d_in[24];
  const float* b_o = (const float*)d_in[25];
  const float* ffn_ln_s = (const float*)d_in[26];
  const float* ffn_ln_b = (const float*)d_in[27];
  const float* w1 = (const float*)d_in[28];
  const float* b1 = (const float*)d_in[29];
  const float* w2 = (const float*)d_in[30];
  const float* b2 = (const float*)d_in[31];
  const float* last_ln_s = (const float*)d_in[32];
  const float* last_ln_b = (const float*)d_in[33];

  float* ws = (float*)d_ws;
  const size_t NBT = (size_t)BT * HDIM;
  // ws layout (8 buffers x 13.1MB = 104.9 MB)
  float* emb = ws;            // [3*BT,128]: log, pos, neg
  float* x   = ws + 3 * NBT;
  float* Qb  = ws + 4 * NBT;  // LN output / y / feats
  float* kb  = ws + 5 * NBT;
  float* vb  = ws + 6 * NBT;
  float* ob  = ws + 7 * NBT;  // attn out / ffn hidden
  float* qb  = emb;           // q reuses emb_log slot (consumed by x0 before first q GEMM)

  // host-side, stream-free; safe under graph capture, same work every call
  hipFuncSetAttribute((const void*)attn_kernel,
                      hipFuncAttributeMaxDynamicSharedMemorySize, 104448);

  item_emb_kernel<<<4800, 256, 0, stream>>>(log_seqs, pos_seqs, neg_seqs,
      txt_table, img_table, txt_ln_s, txt_ln_b, txt_w, txt_b,
      img_ln_s, img_ln_b, img_w, img_b, fuse_w, fuse_b, emb);
  x0_kernel<<<3200, 256, 0, stream>>>(emb, pos_e, log_seqs, x);

  for (int i = 0; i < 2; ++i) {
    const size_t wo = (size_t)i * HDIM * HDIM, bo = (size_t)i * HDIM;
    ln128_kernel<<<6400, 256, 0, stream>>>(x, attn_ln_s + bo, attn_ln_b + bo, Qb, 1e-8f);
    gemm128_kernel<<<800, 256, 0, stream>>>(Qb, w_q + wo, b_q + bo, nullptr, nullptr, qb, 0);
    gemm128_kernel<<<800, 256, 0, stream>>>(x,  w_k + wo, b_k + bo, nullptr, nullptr, kb, 0);
    gemm128_kernel<<<800, 256, 0, stream>>>(x,  w_v + wo, b_v + bo, nullptr, nullptr, vb, 0);
    attn_kernel<<<256, 256, 104448, stream>>>(qb, kb, vb, ob);
    gemm128_kernel<<<800, 256, 0, stream>>>(ob, w_o + wo, b_o + bo, Qb, nullptr, x, 0);
    ln128_kernel<<<6400, 256, 0, stream>>>(x, ffn_ln_s + bo, ffn_ln_b + bo, Qb, 1e-8f);
    gemm128_kernel<<<800, 256, 0, stream>>>(Qb, w1 + wo, b1 + bo, nullptr, nullptr, ob, 1);
    gemm128_kernel<<<800, 256, 0, stream>>>(ob, w2 + wo, b2 + bo, Qb, log_seqs, x, 0);
  }
  ln128_kernel<<<6400, 256, 0, stream>>>(x, last_ln_s, last_ln_b, Qb, 1e-8f);
  logits_kernel<<<6400, 256, 0, stream>>>(Qb, emb + NBT, emb + 2 * NBT, (float*)d_out);
}

// Round 3
// 1076.455 us; speedup vs baseline: 2.3998x; 2.3998x over previous
//
#include <hip/hip_runtime.h>
#include <hip/hip_bf16.h>

#define BATCH 128
#define SEQT  200
#define BT    25600
#define HDIM  128

typedef __attribute__((ext_vector_type(8))) short short8;
typedef __attribute__((ext_vector_type(4))) float f32x4;
typedef __attribute__((ext_vector_type(4))) unsigned short us4;

__device__ __forceinline__ float wave_reduce_sum(float v) {
  #pragma unroll
  for (int o = 32; o; o >>= 1) v += __shfl_xor(v, o);
  return v;
}
__device__ __forceinline__ float wave_reduce_max(float v) {
  #pragma unroll
  for (int o = 32; o; o >>= 1) v = fmaxf(v, __shfl_xor(v, o));
  return v;
}
__device__ __forceinline__ unsigned short f2bf(float f) {
  union { float f; unsigned u; } v; v.f = f;
  unsigned r = v.u + 0x7fffu + ((v.u >> 16) & 1u);
  return (unsigned short)(r >> 16);
}
__device__ __forceinline__ float bflo(unsigned kv) {  // low bf16 of packed pair
  union { unsigned u; float f; } v; v.u = kv << 16; return v.f;
}
__device__ __forceinline__ float bfhi(unsigned kv) {
  union { unsigned u; float f; } v; v.u = kv & 0xffff0000u; return v.f;
}
__device__ __forceinline__ float bf1(unsigned short h) {
  union { unsigned u; float f; } v; v.u = ((unsigned)h) << 16; return v.f;
}

// ---------------- weight prep: fp32 [K][N] -> bf16 W^T [N][K] ----------------
struct WSeg { const float* p; int K; int N; };
struct WTab { WSeg s[15]; };

__global__ __launch_bounds__(256) void prep_w(WTab tab, unsigned short* __restrict__ dst) {
  int e = blockIdx.x * 256 + threadIdx.x;
  int ofs = 0;
  #pragma unroll
  for (int i = 0; i < 15; ++i) {
    int K = tab.s[i].K, N = tab.s[i].N, sz = K * N;
    if (e < sz) {
      int n = e / K, k = e - n * K;
      dst[ofs + e] = f2bf(tab.s[i].p[(size_t)k * N + n]);
      return;
    }
    e -= sz; ofs += sz;
  }
}

// ---------------- fused gather + LN + MFMA tower ----------------
// 32 items/block, 4 waves. LDS: bf16 rows, row stride K+8 ushorts (16B pad).
template<int K>
__global__ __launch_bounds__(256) void tower_kernel(
    const int* __restrict__ log_seqs, const int* __restrict__ pos_seqs, const int* __restrict__ neg_seqs,
    const float* __restrict__ table,
    const float* __restrict__ lns, const float* __restrict__ lnb,
    const unsigned short* __restrict__ wt,   // [64][K] bf16
    const float* __restrict__ bias,          // [64]
    unsigned short* __restrict__ cat, int cofs)
{
  constexpr int ROWE = K + 8;                // ushorts per row
  __shared__ unsigned short lds16[32 * ROWE];
  const int tid = threadIdx.x, w = tid >> 6, l = tid & 63;
  const int item0 = blockIdx.x * 32;
  constexpr int NF = K / 64;                 // floats per lane per row
  float gam[NF], bet[NF];
  #pragma unroll
  for (int i = 0; i < NF / 4; ++i) {
    *(float4*)&gam[i * 4] = *(const float4*)(lns + l * 4 + i * 256);
    *(float4*)&bet[i * 4] = *(const float4*)(lnb + l * 4 + i * 256);
  }
  for (int r8 = 0; r8 < 8; ++r8) {
    int r = w * 8 + r8;
    int idx = item0 + r;
    int seq = idx / BT, pos = idx - seq * BT;
    const int* sp = (seq == 0) ? log_seqs : (seq == 1 ? pos_seqs : neg_seqs);
    int id = sp[pos];
    const float* rowp = table + (size_t)id * K;
    float xv[NF];
    #pragma unroll
    for (int i = 0; i < NF / 4; ++i)
      *(float4*)&xv[i * 4] = *(const float4*)(rowp + l * 4 + i * 256);
    float s = 0.f, sq = 0.f;
    #pragma unroll
    for (int i = 0; i < NF; ++i) { s += xv[i]; sq += xv[i] * xv[i]; }
    s = wave_reduce_sum(s); sq = wave_reduce_sum(sq);
    float mu = s * (1.f / K);
    float rstd = rsqrtf(sq * (1.f / K) - mu * mu + 1e-5f);
    unsigned short o[NF];
    #pragma unroll
    for (int i = 0; i < NF; ++i) o[i] = f2bf((xv[i] - mu) * rstd * gam[i] + bet[i]);
    #pragma unroll
    for (int i = 0; i < NF / 4; ++i)
      *(us4*)&lds16[r * ROWE + l * 4 + i * 256] = *(us4*)&o[i * 4];
  }
  __syncthreads();
  // MFMA: wave -> m-tile (w&1)*16, n-half (w>>1)*32
  const int m0 = (w & 1) * 16, nh = (w >> 1) * 32;
  f32x4 acc0 = {0.f, 0.f, 0.f, 0.f}, acc1 = {0.f, 0.f, 0.f, 0.f};
  const int arow = m0 + (l & 15);
  const int kb8 = (l >> 4) * 8;
  const unsigned short* ap = &lds16[arow * ROWE + kb8];
  const unsigned short* b0p = wt + (size_t)(nh + (l & 15)) * K + kb8;
  const unsigned short* b1p = b0p + 16 * K;
  #pragma unroll
  for (int ks = 0; ks < K / 32; ++ks) {
    short8 a  = *(const short8*)(ap + ks * 32);
    short8 b0 = *(const short8*)(b0p + ks * 32);
    short8 b1 = *(const short8*)(b1p + ks * 32);
    acc0 = __builtin_amdgcn_mfma_f32_16x16x32_bf16(a, b0, acc0, 0, 0, 0);
    acc1 = __builtin_amdgcn_mfma_f32_16x16x32_bf16(a, b1, acc1, 0, 0, 0);
  }
  float bia0 = bias[nh + (l & 15)], bia1 = bias[nh + 16 + (l & 15)];
  #pragma unroll
  for (int reg = 0; reg < 4; ++reg) {
    int row = item0 + m0 + (l >> 4) * 4 + reg;
    unsigned short* cp = cat + (size_t)row * HDIM + cofs;
    cp[nh + (l & 15)]      = f2bf(fmaxf(acc0[reg] + bia0, 0.f));
    cp[nh + 16 + (l & 15)] = f2bf(fmaxf(acc1[reg] + bia1, 0.f));
  }
}

// ---------------- generic MFMA GEMM: [M,128] bf16 x [128,128] ----------------
template<int RELU, int OUTF32, int OUTBF, int ADD, int MASK>
__global__ __launch_bounds__(256) void gemm_bf16_kernel(
    const unsigned short* __restrict__ A, const unsigned short* __restrict__ BT_,
    const float* __restrict__ bias, const float* __restrict__ addp,
    const int* __restrict__ mask, float* __restrict__ outf, unsigned short* __restrict__ outb)
{
  const int tid = threadIdx.x, w = tid >> 6, l = tid & 63;
  const int row0 = blockIdx.x * 64 + w * 16;
  const int kb8 = (l >> 4) * 8;
  const unsigned short* ap = A + (size_t)(row0 + (l & 15)) * 128 + kb8;
  const unsigned short* bp = BT_ + (size_t)(l & 15) * 128 + kb8;
  f32x4 acc[8];
  #pragma unroll
  for (int t = 0; t < 8; ++t) acc[t] = (f32x4){0.f, 0.f, 0.f, 0.f};
  #pragma unroll
  for (int ks = 0; ks < 4; ++ks) {
    short8 a = *(const short8*)(ap + ks * 32);
    #pragma unroll
    for (int t = 0; t < 8; ++t) {
      short8 b = *(const short8*)(bp + (size_t)t * 16 * 128 + ks * 32);
      acc[t] = __builtin_amdgcn_mfma_f32_16x16x32_bf16(a, b, acc[t], 0, 0, 0);
    }
  }
  #pragma unroll
  for (int t = 0; t < 8; ++t) {
    int n = t * 16 + (l & 15);
    float bv = bias[n];
    #pragma unroll
    for (int reg = 0; reg < 4; ++reg) {
      int row = row0 + (l >> 4) * 4 + reg;
      float v = acc[t][reg] + bv;
      if (RELU) v = fmaxf(v, 0.f);
      if (ADD)  v += addp[(size_t)row * 128 + n];
      if (MASK) v = (mask[row] != 0) ? v : 0.f;
      if (OUTF32) outf[(size_t)row * 128 + n] = v;
      if (OUTBF)  outb[(size_t)row * 128 + n] = f2bf(v);
    }
  }
}

// ---------------- x0 = emb_log*sqrt(H) + pos_e, masked; also bf16 copy ----------------
__global__ __launch_bounds__(256) void x0_kernel(const float* __restrict__ emb_log,
    const float* __restrict__ pos_e, const int* __restrict__ log_seqs,
    float* __restrict__ x, unsigned short* __restrict__ xbf)
{
  int e = blockIdx.x * 256 + threadIdx.x;  // float4 index; total BT*32
  int row = e >> 5, c4 = e & 31;
  int t = row % SEQT;
  float4 v = *(const float4*)(emb_log + (size_t)row * HDIM + c4 * 4);
  float4 p = *(const float4*)(pos_e + (size_t)t * HDIM + c4 * 4);
  float kp = (log_seqs[row] != 0) ? 1.f : 0.f;
  const float s = 11.313708498984761f;
  float4 o;
  o.x = (v.x * s + p.x) * kp;
  o.y = (v.y * s + p.y) * kp;
  o.z = (v.z * s + p.z) * kp;
  o.w = (v.w * s + p.w) * kp;
  *(float4*)(x + (size_t)row * HDIM + c4 * 4) = o;
  us4 ob = { f2bf(o.x), f2bf(o.y), f2bf(o.z), f2bf(o.w) };
  *(us4*)(xbf + (size_t)row * HDIM + c4 * 4) = ob;
}

// ---------------- LayerNorm over 128: fp32 in -> bf16 out (+opt fp32) ----------------
template<int OUTF32>
__global__ __launch_bounds__(256) void ln_kernel(const float* __restrict__ in,
    const float* __restrict__ g, const float* __restrict__ b,
    unsigned short* __restrict__ outb, float* __restrict__ outf, float eps)
{
  int row = blockIdx.x * 4 + (threadIdx.x >> 6);
  int lane = threadIdx.x & 63;
  const float* p = in + (size_t)row * HDIM;
  float2 v = *(const float2*)(p + lane * 2);
  float s = wave_reduce_sum(v.x + v.y);
  float sq = wave_reduce_sum(v.x * v.x + v.y * v.y);
  float mu = s * (1.f / 128.f);
  float rs = rsqrtf(sq * (1.f / 128.f) - mu * mu + eps);
  float2 gg = *(const float2*)(g + lane * 2), bb = *(const float2*)(b + lane * 2);
  float2 o;
  o.x = (v.x - mu) * rs * gg.x + bb.x;
  o.y = (v.y - mu) * rs * gg.y + bb.y;
  unsigned pk = (unsigned)f2bf(o.x) | ((unsigned)f2bf(o.y) << 16);
  *(unsigned*)(outb + (size_t)row * HDIM + lane * 2) = pk;
  if (OUTF32) *(float2*)(outf + (size_t)row * HDIM + lane * 2) = o;
}

// ---------------- causal attention: q fp32, k/v bf16 LDS, t-parity split ----------------
__global__ __launch_bounds__(256) void attn_kernel(const float* __restrict__ q,
    const unsigned short* __restrict__ kbuf, const unsigned short* __restrict__ vbuf,
    unsigned short* __restrict__ ao)
{
  __shared__ unsigned short k_lds[SEQT * 64];
  __shared__ unsigned short v_lds[SEQT * 64];
  __shared__ float q_lds[4][64];
  __shared__ float p_lds[4][64];
  const int tid = threadIdx.x;
  const int bh = blockIdx.x >> 2, par = blockIdx.x & 3;
  const int b = bh >> 1, h = bh & 1;
  const size_t base = (size_t)b * SEQT * HDIM + h * 64;
  // stage k/v bf16 with swizzle: element d of row s at d ^ ((s&31)<<1)
  for (int e = tid; e < SEQT * 32; e += 256) {
    int s = e >> 5, u = e & 31;
    int dsw = (2 * u) ^ ((s & 31) << 1);
    *(unsigned*)&k_lds[s * 64 + dsw] = *(const unsigned*)(kbuf + base + (size_t)s * HDIM + 2 * u);
    *(unsigned*)&v_lds[s * 64 + dsw] = *(const unsigned*)(vbuf + base + (size_t)s * HDIM + 2 * u);
  }
  __syncthreads();
  const int w = tid >> 6, l = tid & 63;
  const int mm = (l & 31) << 1;
  for (int t = par + 4 * w; t < SEQT; t += 16) {
    q_lds[w][l] = q[base + (size_t)t * HDIM + l];
    const int nch = (t >> 6) + 1;
    float sc[4], m = -1e30f;
    for (int c = 0; c < nch; ++c) {
      int s = c * 64 + l;
      if (s <= t) {
        const unsigned short* kr = k_lds + s * 64;
        float a = 0.f;
        #pragma unroll
        for (int j = 0; j < 32; ++j) {
          unsigned kv = *(const unsigned*)(kr + ((2 * j) ^ mm));
          a = fmaf(q_lds[w][2 * j],     bflo(kv), a);
          a = fmaf(q_lds[w][2 * j + 1], bfhi(kv), a);
        }
        sc[c] = a * 0.125f;
      } else sc[c] = -1e30f;
      m = fmaxf(m, sc[c]);
    }
    m = wave_reduce_max(m);
    float p[4], ssum = 0.f;
    for (int c = 0; c < nch; ++c) {
      int s = c * 64 + l;
      p[c] = (s <= t) ? __expf(sc[c] - m) : 0.f;
      ssum += p[c];
    }
    ssum = wave_reduce_sum(ssum);
    float inv = 1.f / ssum;
    float oacc = 0.f;
    for (int c = 0; c < nch; ++c) {
      p_lds[w][l] = p[c];
      const int smax = min(64, t - c * 64 + 1);
      for (int sp = 0; sp < smax; ++sp) {
        int s = c * 64 + sp;
        oacc = fmaf(p_lds[w][sp], bf1(v_lds[s * 64 + (l ^ ((s & 31) << 1))]), oacc);
      }
    }
    ao[base + (size_t)t * HDIM + l] = f2bf(oacc * inv);
  }
}

// ---------------- logits: fp32 feats, fp32 emb ----------------
__global__ __launch_bounds__(256) void logits_kernel(const float* __restrict__ feats,
    const float* __restrict__ ep, const float* __restrict__ en, float* __restrict__ out)
{
  int row = blockIdx.x * 4 + (threadIdx.x >> 6);
  int lane = threadIdx.x & 63;
  size_t off = (size_t)row * HDIM + lane * 2;
  float2 f = *(const float2*)(feats + off);
  float2 p = *(const float2*)(ep + off);
  float2 n = *(const float2*)(en + off);
  float sp = wave_reduce_sum(f.x * p.x + f.y * p.y);
  float sn = wave_reduce_sum(f.x * n.x + f.y * n.y);
  if (lane == 0) { out[row] = sp; out[BT + row] = sn; }
}

extern "C" void kernel_launch(void* const* d_in, const int* in_sizes, int n_in,
                              void* d_out, int out_size, void* d_ws, size_t ws_size,
                              hipStream_t stream) {
  const int* log_seqs   = (const int*)d_in[0];
  const int* pos_seqs   = (const int*)d_in[1];
  const int* neg_seqs   = (const int*)d_in[2];
  const float* txt_table = (const float*)d_in[3];
  const float* img_table = (const float*)d_in[4];
  const float* txt_ln_s = (const float*)d_in[5];
  const float* txt_ln_b = (const float*)d_in[6];
  const float* txt_w    = (const float*)d_in[7];
  const float* txt_b    = (const float*)d_in[8];
  const float* img_ln_s = (const float*)d_in[9];
  const float* img_ln_b = (const float*)d_in[10];
  const float* img_w    = (const float*)d_in[11];
  const float* img_b    = (const float*)d_in[12];
  const float* fuse_w   = (const float*)d_in[13];
  const float* fuse_b   = (const float*)d_in[14];
  const float* pos_e    = (const float*)d_in[15];
  const float* attn_ln_s = (const float*)d_in[16];
  const float* attn_ln_b = (const float*)d_in[17];
  const float* w_q = (const float*)d_in[18];
  const float* b_q = (const float*)d_in[19];
  const float* w_k = (const float*)d_in[20];
  const float* b_k = (const float*)d_in[21];
  const float* w_v = (const float*)d_in[22];
  const float* b_v = (const float*)d_in[23];
  const float* w_o = (const float*)d_in[24];
  const float* b_o = (const float*)d_in[25];
  const float* ffn_ln_s = (const float*)d_in[26];
  const float* ffn_ln_b = (const float*)d_in[27];
  const float* w1 = (const float*)d_in[28];
  const float* b1 = (const float*)d_in[29];
  const float* w2 = (const float*)d_in[30];
  const float* b2 = (const float*)d_in[31];
  const float* last_ln_s = (const float*)d_in[32];
  const float* last_ln_b = (const float*)d_in[33];

  float* ws = (float*)d_ws;
  // float-unit offsets
  unsigned short* wt = (unsigned short*)ws;                  // 294912 ush (<1MB region)
  float* emb  = ws + 262144;            // fp32 [76800][128] = 39.3 MB
  float* x    = ws + 10092544;          // fp32 [25600][128]
  float* Qb   = ws + 13369344;          // fp32 residual / feats
  unsigned short* ybf  = (unsigned short*)(ws + 16646144);   // bf16 [25600][128]
  float* qb   = ws + 18284544;          // fp32 q
  unsigned short* kbbf = (unsigned short*)(ws + 21561344);   // bf16 k
  unsigned short* vbbf = (unsigned short*)(ws + 23199744);   // bf16 v
  unsigned short* aohbf = (unsigned short*)(ws + 24838144);  // bf16 attn-out / ffn-hidden
  unsigned short* xbf  = (unsigned short*)(ws + 26476544);   // bf16 copy of x
  unsigned short* cat  = (unsigned short*)qb;                // bf16 [76800][128], dead before qb used

  // weight table (order fixes wt offsets)
  WTab tab;
  tab.s[0] = {txt_w, 768, 64};
  tab.s[1] = {img_w, 512, 64};
  tab.s[2] = {fuse_w, 128, 128};
  const float* lw[6] = {w_q, w_k, w_v, w_o, w1, w2};
  for (int m = 0; m < 6; ++m)
    for (int i = 0; i < 2; ++i)
      tab.s[3 + m * 2 + i] = {lw[m] + (size_t)i * 16384, 128, 128};
  const int WOF_TXT = 0, WOF_IMG = 49152, WOF_FUSE = 81920, WOF_L = 98304;

  prep_w<<<1152, 256, 0, stream>>>(tab, wt);
  tower_kernel<768><<<2400, 256, 0, stream>>>(log_seqs, pos_seqs, neg_seqs,
      txt_table, txt_ln_s, txt_ln_b, wt + WOF_TXT, txt_b, cat, 0);
  tower_kernel<512><<<2400, 256, 0, stream>>>(log_seqs, pos_seqs, neg_seqs,
      img_table, img_ln_s, img_ln_b, wt + WOF_IMG, img_b, cat, 64);
  gemm_bf16_kernel<1,1,0,0,0><<<1200, 256, 0, stream>>>(cat, wt + WOF_FUSE, fuse_b,
      nullptr, nullptr, emb, nullptr);
  x0_kernel<<<3200, 256, 0, stream>>>(emb, pos_e, log_seqs, x, xbf);

  for (int i = 0; i < 2; ++i) {
    const size_t bo = (size_t)i * HDIM;
    const unsigned short* WTq = wt + WOF_L + (0 * 2 + i) * 16384;
    const unsigned short* WTk = wt + WOF_L + (1 * 2 + i) * 16384;
    const unsigned short* WTv = wt + WOF_L + (2 * 2 + i) * 16384;
    const unsigned short* WTo = wt + WOF_L + (3 * 2 + i) * 16384;
    const unsigned short* WT1 = wt + WOF_L + (4 * 2 + i) * 16384;
    const unsigned short* WT2 = wt + WOF_L + (5 * 2 + i) * 16384;
    ln_kernel<1><<<6400, 256, 0, stream>>>(x, attn_ln_s + bo, attn_ln_b + bo, ybf, Qb, 1e-8f);
    gemm_bf16_kernel<0,1,0,0,0><<<400, 256, 0, stream>>>(ybf, WTq, b_q + bo, nullptr, nullptr, qb, nullptr);
    gemm_bf16_kernel<0,0,1,0,0><<<400, 256, 0, stream>>>(xbf, WTk, b_k + bo, nullptr, nullptr, nullptr, kbbf);
    gemm_bf16_kernel<0,0,1,0,0><<<400, 256, 0, stream>>>(xbf, WTv, b_v + bo, nullptr, nullptr, nullptr, vbbf);
    attn_kernel<<<1024, 256, 0, stream>>>(qb, kbbf, vbbf, aohbf);
    gemm_bf16_kernel<0,1,1,1,0><<<400, 256, 0, stream>>>(aohbf, WTo, b_o + bo, Qb, nullptr, x, xbf);
    ln_kernel<1><<<6400, 256, 0, stream>>>(x, ffn_ln_s + bo, ffn_ln_b + bo, ybf, Qb, 1e-8f);
    gemm_bf16_kernel<1,0,1,0,0><<<400, 256, 0, stream>>>(ybf, WT1, b1 + bo, nullptr, nullptr, nullptr, aohbf);
    gemm_bf16_kernel<0,1,1,1,1><<<400, 256, 0, stream>>>(aohbf, WT2, b2 + bo, Qb, log_seqs, x, xbf);
  }
  ln_kernel<1><<<6400, 256, 0, stream>>>(x, last_ln_s, last_ln_b, ybf, Qb, 1e-8f);
  logits_kernel<<<6400, 256, 0, stream>>>(Qb, emb + (size_t)BT * HDIM, emb + 2 * (size_t)BT * HDIM, (float*)d_out);
}